// Round 1
// baseline (310.868 us; speedup 1.0000x reference)
//
#include <hip/hip_runtime.h>

#define BB 64
#define TT 512
#define HH 768
#define KK 11
#define START_ID 9
#define NEGV -10000.0f

// ---------------------------------------------------------------------------
// FC kernel: feats[b,t,k] = dot(embeds[b,t,:], W_fc[k,:]) + b_fc[k]
// One wave per (b,t) row. W_fc fragment lives in VGPRs (amortized over rows).
// Lane l covers h = l*12 .. l*12+11 (3x float4, coalesced 3KB row reads).
// ---------------------------------------------------------------------------
__global__ __launch_bounds__(256) void fc_kernel(const float* __restrict__ embeds,
                                                 const float* __restrict__ W,
                                                 const float* __restrict__ bias,
                                                 float* __restrict__ feats) {
    const int lane = threadIdx.x & 63;
    const int wave_in_block = threadIdx.x >> 6;
    const int waves_per_grid = (gridDim.x * blockDim.x) >> 6;
    const int wave_id = blockIdx.x * (blockDim.x >> 6) + wave_in_block;

    // Preload W fragment: wf[k][r] = W[k][lane*12 + r*4 .. +3]
    float4 wf[KK][3];
#pragma unroll
    for (int k = 0; k < KK; ++k) {
#pragma unroll
        for (int r = 0; r < 3; ++r) {
            wf[k][r] = *reinterpret_cast<const float4*>(W + k * HH + lane * 12 + r * 4);
        }
    }
    const float bk = (lane < KK) ? bias[lane] : 0.0f;

    for (int row = wave_id; row < BB * TT; row += waves_per_grid) {
        const float* e = embeds + (size_t)row * HH + lane * 12;
        float4 e0 = *reinterpret_cast<const float4*>(e);
        float4 e1 = *reinterpret_cast<const float4*>(e + 4);
        float4 e2 = *reinterpret_cast<const float4*>(e + 8);

        float acc[KK];
#pragma unroll
        for (int k = 0; k < KK; ++k) {
            float4 w0 = wf[k][0], w1 = wf[k][1], w2 = wf[k][2];
            acc[k] = e0.x * w0.x + e0.y * w0.y + e0.z * w0.z + e0.w * w0.w
                   + e1.x * w1.x + e1.y * w1.y + e1.z * w1.z + e1.w * w1.w
                   + e2.x * w2.x + e2.y * w2.y + e2.z * w2.z + e2.w * w2.w;
        }
        // butterfly reduce each acc[k] across the 64-lane wave
#pragma unroll
        for (int off = 1; off < 64; off <<= 1) {
#pragma unroll
            for (int k = 0; k < KK; ++k) {
                acc[k] += __shfl_xor(acc[k], off, 64);
            }
        }
        if (lane < KK) {
            float v = acc[0];
#pragma unroll
            for (int k = 1; k < KK; ++k) v = (lane == k) ? acc[k] : v;
            feats[(size_t)row * KK + lane] = v + bk;
        }
    }
}

// ---------------------------------------------------------------------------
// Viterbi kernel: one block (one wave) per batch element.
// Lane i (< 11) owns tag i. feats[b] staged in LDS; psi kept in LDS.
// Forward: delta broadcast via __shfl (constant lane -> readlane),
// strict '>' scan == jnp.argmax first-occurrence tie semantics.
// Backtrack: lane i reads psi_t[i] (independent of tag chain), then one
// __shfl with the dynamic tag (ds_bpermute) per step.
// ---------------------------------------------------------------------------
__global__ __launch_bounds__(64) void viterbi_kernel(const float* __restrict__ feats,
                                                     const float* __restrict__ trans,
                                                     float* __restrict__ out) {
    __shared__ float feats_lds[TT * KK];        // 22528 B
    __shared__ int psi_lds[(TT - 1) * KK];      // 22484 B

    const int b = blockIdx.x;
    const int lane = threadIdx.x;
    const int i = lane;
    const int ci = (lane < KK) ? lane : (KK - 1);   // clamped index for safe LDS reads

    // stage feats[b] (5632 floats = 1408 float4) into LDS
    const float4* src = reinterpret_cast<const float4*>(feats + (size_t)b * TT * KK);
    float4* dst = reinterpret_cast<float4*>(feats_lds);
    for (int idx = lane; idx < TT * KK / 4; idx += 64) dst[idx] = src[idx];

    // transitions row for this lane's tag
    float tr[KK];
    if (i < KK) {
#pragma unroll
        for (int j = 0; j < KK; ++j) tr[j] = trans[i * KK + j];
    } else {
#pragma unroll
        for (int j = 0; j < KK; ++j) tr[j] = NEGV;
    }
    __syncthreads();

    float delta = (i == START_ID) ? 0.0f : NEGV;

    for (int t = 1; t < TT; ++t) {
        // broadcast all delta_j (constant-lane shuffles -> readlane)
        float dj[KK];
#pragma unroll
        for (int j = 0; j < KK; ++j) dj[j] = __shfl(delta, j, 64);

        float best = tr[0] + dj[0];
        int bj = 0;
#pragma unroll
        for (int j = 1; j < KK; ++j) {
            float s = tr[j] + dj[j];
            bool c = s > best;           // strict: first max wins (ties -> lower j)
            best = c ? s : best;
            bj = c ? j : bj;
        }
        float feat = feats_lds[t * KK + ci];
        delta = best + feat;
        if (i < KK) psi_lds[(t - 1) * KK + i] = bj;
    }
    __syncthreads();

    // final score + last tag (computed redundantly in all lanes)
    float best = __shfl(delta, 0, 64);
    int bj = 0;
#pragma unroll
    for (int j = 1; j < KK; ++j) {
        float s = __shfl(delta, j, 64);
        bool c = s > best;
        best = c ? s : best;
        bj = c ? j : bj;
    }

    float* path_out = out + BB + (size_t)b * TT;
    if (lane == 0) {
        out[b] = best;
        path_out[TT - 1] = (float)bj;
    }

    int tag = bj;  // uniform across lanes
    for (int t = TT - 2; t >= 0; --t) {
        int p = psi_lds[t * KK + ci];       // lane i holds psi_t[i]; prefetchable
        tag = __shfl(p, tag, 64);           // ds_bpermute with uniform dynamic lane
        if (lane == 0) path_out[t] = (float)tag;
    }
}

extern "C" void kernel_launch(void* const* d_in, const int* in_sizes, int n_in,
                              void* d_out, int out_size, void* d_ws, size_t ws_size,
                              hipStream_t stream) {
    const float* embeds = (const float*)d_in[0];  // [B,T,H]
    const float* W_fc   = (const float*)d_in[1];  // [K,H]
    const float* b_fc   = (const float*)d_in[2];  // [K]
    const float* trans  = (const float*)d_in[3];  // [K,K]
    float* out = (float*)d_out;                   // [B] score ++ [B,T] path (as float)
    float* feats = (float*)d_ws;                  // [B,T,K] scratch: 1.44 MB

    fc_kernel<<<1024, 256, 0, stream>>>(embeds, W_fc, b_fc, feats);
    viterbi_kernel<<<BB, 64, 0, stream>>>(feats, trans, out);
}

// Round 2
// 208.810 us; speedup vs baseline: 1.4888x; 1.4888x over previous
//
#include <hip/hip_runtime.h>

#define BB 64
#define TT 512
#define HH 768
#define KK 11
#define START_ID 9
#define NEGV -10000.0f

// ---------------------------------------------------------------------------
// DPP wave-64 sum reduction: row_shr 1/2/4/8 + row_bcast:15 + row_bcast:31.
// Result lands in lane 63. VALU-path only (no LDS), ~4 cyc per stage.
// ---------------------------------------------------------------------------
template <int CTRL>
__device__ __forceinline__ float dpp_add(float x) {
    int yi = __builtin_amdgcn_update_dpp(0, __float_as_int(x), CTRL, 0xF, 0xF, false);
    return x + __int_as_float(yi);
}

__device__ __forceinline__ float wave_sum_to_lane63(float x) {
    x = dpp_add<0x111>(x);  // row_shr:1
    x = dpp_add<0x112>(x);  // row_shr:2
    x = dpp_add<0x114>(x);  // row_shr:4
    x = dpp_add<0x118>(x);  // row_shr:8  -> lane 15 of each row16 has row sum
    x = dpp_add<0x142>(x);  // row_bcast:15 -> lane63 += sum(32..47)
    x = dpp_add<0x143>(x);  // row_bcast:31 -> lane63 += sum(0..31)
    return x;               // lane 63 = full 64-lane sum
}

__device__ __forceinline__ float rlane(float v, int l) {
    return __int_as_float(__builtin_amdgcn_readlane(__float_as_int(v), l));
}

// ---------------------------------------------------------------------------
// FC: feats[row,k] = dot(embeds[row,:], W[k,:]) + b[k].  One wave per row.
// Lane l holds embed floats {4l..4l+3, 256+4l.., 512+4l..} -> three perfectly
// coalesced 1KB float4 loads. W fragments live in VGPRs (132 regs), amortized
// over 8 rows/wave. Reduction via DPP (no LDS path).
// ---------------------------------------------------------------------------
__global__ __launch_bounds__(256) void fc_kernel(const float* __restrict__ embeds,
                                                 const float* __restrict__ W,
                                                 const float* __restrict__ bias,
                                                 float* __restrict__ feats) {
    const int lane = threadIdx.x & 63;
    const int wave_id = (blockIdx.x * blockDim.x + threadIdx.x) >> 6;
    const int nwaves = (gridDim.x * blockDim.x) >> 6;

    float4 wf[KK][3];
#pragma unroll
    for (int k = 0; k < KK; ++k) {
        wf[k][0] = *reinterpret_cast<const float4*>(W + k * HH + 0   + lane * 4);
        wf[k][1] = *reinterpret_cast<const float4*>(W + k * HH + 256 + lane * 4);
        wf[k][2] = *reinterpret_cast<const float4*>(W + k * HH + 512 + lane * 4);
    }
    float bk[KK];
#pragma unroll
    for (int k = 0; k < KK; ++k) bk[k] = bias[k];  // uniform -> SGPRs

    for (int row = wave_id; row < BB * TT; row += nwaves) {
        const float* e = embeds + (size_t)row * HH;
        float4 e0 = *reinterpret_cast<const float4*>(e + 0   + lane * 4);
        float4 e1 = *reinterpret_cast<const float4*>(e + 256 + lane * 4);
        float4 e2 = *reinterpret_cast<const float4*>(e + 512 + lane * 4);

        float acc[KK];
#pragma unroll
        for (int k = 0; k < KK; ++k) {
            float4 w0 = wf[k][0], w1 = wf[k][1], w2 = wf[k][2];
            acc[k] = e0.x * w0.x + e0.y * w0.y + e0.z * w0.z + e0.w * w0.w
                   + e1.x * w1.x + e1.y * w1.y + e1.z * w1.z + e1.w * w1.w
                   + e2.x * w2.x + e2.y * w2.y + e2.z * w2.z + e2.w * w2.w;
        }
#pragma unroll
        for (int k = 0; k < KK; ++k) acc[k] = wave_sum_to_lane63(acc[k]);

        if (lane == 63) {
#pragma unroll
            for (int k = 0; k < KK; ++k) feats[(size_t)row * KK + k] = acc[k] + bk[k];
        }
    }
}

// ---------------------------------------------------------------------------
// Viterbi: one block (256 thr) per batch.
// Phase 1 (wave 0): forward value-max only. Lane i = tag i. Broadcast delta
//   via v_readlane (no LDS path), max3 tree (depth 3), delta history -> LDS.
// Phase 2 (all waves): recompute psi[s][i] bit-exactly from delta history,
//   fully parallel over (s,i).
// Phase 3: chunked backtrack — 15 parallel 32-step composition walks +
//   chunk 15 real walk, 15-step boundary chain, 15 parallel re-walks.
// ---------------------------------------------------------------------------
__global__ __launch_bounds__(256) void viterbi_kernel(const float* __restrict__ feats,
                                                      const float* __restrict__ trans,
                                                      float* __restrict__ out) {
    __shared__ __align__(16) float feats_lds[TT * KK];      // 22528 B
    __shared__ __align__(16) float dh[(TT - 1) * 12];       // 24528 B, stride 12 (48B, b128-aligned)
    __shared__ int psi_lds[(TT - 1) * KK];                  // 22484 B
    __shared__ float tr_lds[KK * KK];
    __shared__ int comp[15 * KK];
    __shared__ int bt[16];
    __shared__ int sh_last;

    const int tid = threadIdx.x;
    const int b = blockIdx.x;

    // stage feats[b] + transitions
    {
        const float4* src = reinterpret_cast<const float4*>(feats + (size_t)b * TT * KK);
        float4* dst = reinterpret_cast<float4*>(feats_lds);
        for (int i = tid; i < TT * KK / 4; i += 256) dst[i] = src[i];
        if (tid < KK * KK) tr_lds[tid] = trans[tid];
    }
    __syncthreads();

    // ---- Phase 1: forward (wave 0 only) ----
    if (tid < 64) {
        const int i = tid;
        const int ci = (i < KK) ? i : 0;
        float tr[KK];
#pragma unroll
        for (int j = 0; j < KK; ++j) tr[j] = (i < KK) ? tr_lds[i * KK + j] : NEGV;

        float delta = (i == START_ID) ? 0.0f : NEGV;
        float feat_cur = feats_lds[1 * KK + ci];

        for (int t = 1; t < TT; ++t) {
            if (i < KK) dh[(t - 1) * 12 + i] = delta;           // history (off-chain)
            int nt = (t + 1 < TT) ? (t + 1) : 1;
            float feat_next = feats_lds[nt * KK + ci];          // prefetch (off-chain)

            float dj[KK];
#pragma unroll
            for (int j = 0; j < KK; ++j) dj[j] = rlane(delta, j);
            float s[KK];
#pragma unroll
            for (int j = 0; j < KK; ++j) s[j] = tr[j] + dj[j];
            float t0 = fmaxf(fmaxf(s[0], s[1]), s[2]);
            float t1 = fmaxf(fmaxf(s[3], s[4]), s[5]);
            float t2 = fmaxf(fmaxf(s[6], s[7]), s[8]);
            float t3 = fmaxf(s[9], s[10]);
            float best = fmaxf(fmaxf(fmaxf(t0, t1), t2), t3);
            delta = best + feat_cur;
            feat_cur = feat_next;
        }

        // score + last tag (strict-first argmax, exact)
        float dfin[KK];
#pragma unroll
        for (int j = 0; j < KK; ++j) dfin[j] = rlane(delta, j);
        float best = dfin[0];
        int last = 0;
#pragma unroll
        for (int j = 1; j < KK; ++j) {
            bool c = dfin[j] > best;
            best = c ? dfin[j] : best;
            last = c ? j : last;
        }
        if (tid == 0) {
            out[b] = best;
            out[BB + (size_t)b * TT + (TT - 1)] = (float)last;
            sh_last = last;
        }
    }
    __syncthreads();

    // ---- Phase 2: psi recompute, parallel over (s, i) ----
    {
        const int i = tid & 15;
        const int sg = tid >> 4;
        if (i < KK) {
            float tri[KK];
#pragma unroll
            for (int j = 0; j < KK; ++j) tri[j] = tr_lds[i * KK + j];
            for (int s = sg; s < TT - 1; s += 16) {
                const float4* dr = reinterpret_cast<const float4*>(dh + s * 12);
                float4 a = dr[0], c4 = dr[1], d4 = dr[2];
                float sc[KK] = {tri[0] + a.x,  tri[1] + a.y,  tri[2] + a.z,  tri[3] + a.w,
                                tri[4] + c4.x, tri[5] + c4.y, tri[6] + c4.z, tri[7] + c4.w,
                                tri[8] + d4.x, tri[9] + d4.y, tri[10] + d4.z};
                float bv = sc[0];
                int bj = 0;
#pragma unroll
                for (int j = 1; j < KK; ++j) {
                    bool c = sc[j] > bv;        // strict: first max wins
                    bv = c ? sc[j] : bv;
                    bj = c ? j : bj;
                }
                psi_lds[s * KK + i] = bj;
            }
        }
    }
    __syncthreads();

    // ---- Phase 3a: chunk composition walks (chunks 0..14) + chunk 15 real walk ----
    {
        const int c = tid >> 4;
        const int i = tid & 15;
        if (c < 15 && i < KK) {
            int cur = i;
            for (int s = c * 32 + 31; s >= c * 32; --s) cur = psi_lds[s * KK + cur];
            comp[c * KK + i] = cur;            // path[32c] given path[32(c+1)] = i
        } else if (c == 15 && i == 0) {
            int cur = sh_last;
            float* po = out + BB + (size_t)b * TT;
            for (int s = TT - 2; s >= 480; --s) {
                cur = psi_lds[s * KK + cur];
                po[s] = (float)cur;
            }
            bt[15] = cur;                      // = path[480]
        }
    }
    __syncthreads();

    // ---- Phase 3b: boundary chain (path[32c] for c = 14..1) ----
    if (tid == 0) {
        for (int c = 14; c >= 1; --c) bt[c] = comp[c * KK + bt[c + 1]];
    }
    __syncthreads();

    // ---- Phase 3c: parallel re-walks, store path ----
    if (tid < 15) {
        const int c = tid;
        int cur = bt[c + 1];                   // path[32(c+1)]
        float* po = out + BB + (size_t)b * TT;
        for (int s = c * 32 + 31; s >= c * 32; --s) {
            cur = psi_lds[s * KK + cur];
            po[s] = (float)cur;
        }
    }
}

extern "C" void kernel_launch(void* const* d_in, const int* in_sizes, int n_in,
                              void* d_out, int out_size, void* d_ws, size_t ws_size,
                              hipStream_t stream) {
    const float* embeds = (const float*)d_in[0];  // [B,T,H]
    const float* W_fc   = (const float*)d_in[1];  // [K,H]
    const float* b_fc   = (const float*)d_in[2];  // [K]
    const float* trans  = (const float*)d_in[3];  // [K,K]
    float* out = (float*)d_out;                   // [B] score ++ [B,T] path (as float)
    float* feats = (float*)d_ws;                  // [B,T,K] scratch

    fc_kernel<<<1024, 256, 0, stream>>>(embeds, W_fc, b_fc, feats);
    viterbi_kernel<<<BB, 256, 0, stream>>>(feats, trans, out);
}

// Round 3
// 202.898 us; speedup vs baseline: 1.5321x; 1.0291x over previous
//
#include <hip/hip_runtime.h>

#define BB 64
#define TT 512
#define HH 768
#define KK 11
#define START_ID 9
#define NEGV -10000.0f

typedef float vf2 __attribute__((ext_vector_type(2)));

// ---------------------------------------------------------------------------
// DPP wave-64 sum reduction: row_shr 1/2/4/8 + row_bcast:15 + row_bcast:31.
// Result lands in lane 63. VALU-path only (no LDS).
// ---------------------------------------------------------------------------
template <int CTRL>
__device__ __forceinline__ float dpp_add(float x) {
    int yi = __builtin_amdgcn_update_dpp(0, __float_as_int(x), CTRL, 0xF, 0xF, false);
    return x + __int_as_float(yi);
}

__device__ __forceinline__ float wave_sum_to_lane63(float x) {
    x = dpp_add<0x111>(x);  // row_shr:1
    x = dpp_add<0x112>(x);  // row_shr:2
    x = dpp_add<0x114>(x);  // row_shr:4
    x = dpp_add<0x118>(x);  // row_shr:8  -> lane15 of each row16 = row sum
    x = dpp_add<0x142>(x);  // row_bcast:15
    x = dpp_add<0x143>(x);  // row_bcast:31 -> lane63 = full sum
    return x;
}

__device__ __forceinline__ float rlane(float v, int l) {
    return __int_as_float(__builtin_amdgcn_readlane(__float_as_int(v), l));
}

// ---------------------------------------------------------------------------
// FC: feats[row,k] = dot(embeds[row,:], W[k,:]) + b[k].  One wave per row,
// 8 consecutive rows per wave, 2 rows per iteration (6 x 1KB loads in
// flight). Dot products as <2 x float> so the backend can emit v_pk_fma_f32.
// ---------------------------------------------------------------------------
__global__ __launch_bounds__(256) void fc_kernel(const float* __restrict__ embeds,
                                                 const float* __restrict__ W,
                                                 const float* __restrict__ bias,
                                                 float* __restrict__ feats) {
    const int lane = threadIdx.x & 63;
    const int wave_id = (blockIdx.x * blockDim.x + threadIdx.x) >> 6;

    float4 wf[KK][3];
#pragma unroll
    for (int k = 0; k < KK; ++k)
#pragma unroll
        for (int r = 0; r < 3; ++r)
            wf[k][r] = *reinterpret_cast<const float4*>(W + k * HH + r * 256 + lane * 4);

    float bk[KK];
#pragma unroll
    for (int k = 0; k < KK; ++k) bk[k] = bias[k];  // uniform -> SGPRs

    const int base = wave_id * 8;
#pragma unroll 1
    for (int rr = 0; rr < 8; rr += 2) {
        const float* ea = embeds + (size_t)(base + rr) * HH;
        const float* eb = ea + HH;
        float4 a0 = *reinterpret_cast<const float4*>(ea + 0   + lane * 4);
        float4 a1 = *reinterpret_cast<const float4*>(ea + 256 + lane * 4);
        float4 a2 = *reinterpret_cast<const float4*>(ea + 512 + lane * 4);
        float4 b0 = *reinterpret_cast<const float4*>(eb + 0   + lane * 4);
        float4 b1 = *reinterpret_cast<const float4*>(eb + 256 + lane * 4);
        float4 b2 = *reinterpret_cast<const float4*>(eb + 512 + lane * 4);

        vf2 va[6] = {{a0.x, a0.y}, {a0.z, a0.w}, {a1.x, a1.y},
                     {a1.z, a1.w}, {a2.x, a2.y}, {a2.z, a2.w}};
        vf2 vb[6] = {{b0.x, b0.y}, {b0.z, b0.w}, {b1.x, b1.y},
                     {b1.z, b1.w}, {b2.x, b2.y}, {b2.z, b2.w}};

        float rA[KK], rB[KK];
#pragma unroll
        for (int k = 0; k < KK; ++k) {
            vf2 wv[6] = {{wf[k][0].x, wf[k][0].y}, {wf[k][0].z, wf[k][0].w},
                         {wf[k][1].x, wf[k][1].y}, {wf[k][1].z, wf[k][1].w},
                         {wf[k][2].x, wf[k][2].y}, {wf[k][2].z, wf[k][2].w}};
            vf2 sA = va[0] * wv[0];
            vf2 sB = vb[0] * wv[0];
#pragma unroll
            for (int r = 1; r < 6; ++r) { sA += va[r] * wv[r]; sB += vb[r] * wv[r]; }
            rA[k] = wave_sum_to_lane63(sA.x + sA.y);
            rB[k] = wave_sum_to_lane63(sB.x + sB.y);
        }
        if (lane == 63) {
            float* oA = feats + (size_t)(base + rr) * KK;
#pragma unroll
            for (int k = 0; k < KK; ++k) oA[k] = rA[k] + bk[k];
#pragma unroll
            for (int k = 0; k < KK; ++k) oA[KK + k] = rB[k] + bk[k];
        }
    }
}

// ---------------------------------------------------------------------------
// Viterbi: one block (256 thr) per batch.
// Phase 1 (wave 0): forward value-max, unroll x4 with a 4-deep feat prefetch
//   ring (~240 cyc slack > 120 cyc ds_read latency). feats_lds padded +4 rows
//   so ring prefetch never goes OOB. delta history -> LDS.
// Phase 2: psi recompute bit-exactly from delta history, parallel over (s,i).
// Phase 3: chunked backtrack (15 composition walks + boundary chain + re-walks).
// ---------------------------------------------------------------------------
__global__ __launch_bounds__(256) void viterbi_kernel(const float* __restrict__ feats,
                                                      const float* __restrict__ trans,
                                                      float* __restrict__ out) {
    __shared__ __align__(16) float feats_lds[(TT + 4) * KK];  // +4 pad rows for ring
    __shared__ __align__(16) float dh[(TT - 1) * 12];         // stride 12 (48B)
    __shared__ int psi_lds[(TT - 1) * KK];
    __shared__ float tr_lds[KK * KK];
    __shared__ int comp[15 * KK];
    __shared__ int bt[16];
    __shared__ int sh_last;

    const int tid = threadIdx.x;
    const int b = blockIdx.x;

    {
        const float4* src = reinterpret_cast<const float4*>(feats + (size_t)b * TT * KK);
        float4* dst = reinterpret_cast<float4*>(feats_lds);
        for (int i = tid; i < TT * KK / 4; i += 256) dst[i] = src[i];
        if (tid < KK * KK) tr_lds[tid] = trans[tid];
    }
    __syncthreads();

    // ---- Phase 1: forward (wave 0 only) ----
    if (tid < 64) {
        const int i = tid;
        const int ci = (i < KK) ? i : 0;
        float tr[KK];
#pragma unroll
        for (int j = 0; j < KK; ++j) tr[j] = (i < KK) ? tr_lds[i * KK + j] : NEGV;

        float delta = (i == START_ID) ? 0.0f : NEGV;

        auto vstep = [&](int t, float fcur) {
            if (i < KK) dh[(t - 1) * 12 + i] = delta;   // pre-step delta (off-chain)
            float dj[KK];
#pragma unroll
            for (int j = 0; j < KK; ++j) dj[j] = rlane(delta, j);
            float s[KK];
#pragma unroll
            for (int j = 0; j < KK; ++j) s[j] = tr[j] + dj[j];
            float t0 = fmaxf(fmaxf(s[0], s[1]), s[2]);
            float t1 = fmaxf(fmaxf(s[3], s[4]), s[5]);
            float t2 = fmaxf(fmaxf(s[6], s[7]), s[8]);
            float t3 = fmaxf(s[9], s[10]);
            float best = fmaxf(fmaxf(fmaxf(t0, t1), t2), t3);
            delta = best + fcur;
        };

        float fr0 = feats_lds[1 * KK + ci];
        float fr1 = feats_lds[2 * KK + ci];
        float fr2 = feats_lds[3 * KK + ci];
        float fr3 = feats_lds[4 * KK + ci];

        int t = 1;
#pragma unroll 1
        for (; t <= TT - 4; t += 4) {
            vstep(t,     fr0); fr0 = feats_lds[(t + 4) * KK + ci];
            vstep(t + 1, fr1); fr1 = feats_lds[(t + 5) * KK + ci];
            vstep(t + 2, fr2); fr2 = feats_lds[(t + 6) * KK + ci];
            vstep(t + 3, fr3); fr3 = feats_lds[(t + 7) * KK + ci];
        }
        // t == 509: remaining steps 509,510,511
        vstep(TT - 3, fr0);
        vstep(TT - 2, fr1);
        vstep(TT - 1, fr2);

        // score + last tag (strict-first argmax, exact)
        float dfin[KK];
#pragma unroll
        for (int j = 0; j < KK; ++j) dfin[j] = rlane(delta, j);
        float best = dfin[0];
        int last = 0;
#pragma unroll
        for (int j = 1; j < KK; ++j) {
            bool c = dfin[j] > best;
            best = c ? dfin[j] : best;
            last = c ? j : last;
        }
        if (tid == 0) {
            out[b] = best;
            out[BB + (size_t)b * TT + (TT - 1)] = (float)last;
            sh_last = last;
        }
    }
    __syncthreads();

    // ---- Phase 2: psi recompute, parallel over (s, i) ----
    {
        const int i = tid & 15;
        const int sg = tid >> 4;
        if (i < KK) {
            float tri[KK];
#pragma unroll
            for (int j = 0; j < KK; ++j) tri[j] = tr_lds[i * KK + j];
            for (int s = sg; s < TT - 1; s += 16) {
                const float4* dr = reinterpret_cast<const float4*>(dh + s * 12);
                float4 a = dr[0], c4 = dr[1], d4 = dr[2];
                float sc[KK] = {tri[0] + a.x,  tri[1] + a.y,  tri[2] + a.z,  tri[3] + a.w,
                                tri[4] + c4.x, tri[5] + c4.y, tri[6] + c4.z, tri[7] + c4.w,
                                tri[8] + d4.x, tri[9] + d4.y, tri[10] + d4.z};
                float bv = sc[0];
                int bj = 0;
#pragma unroll
                for (int j = 1; j < KK; ++j) {
                    bool c = sc[j] > bv;        // strict: first max wins
                    bv = c ? sc[j] : bv;
                    bj = c ? j : bj;
                }
                psi_lds[s * KK + i] = bj;
            }
        }
    }
    __syncthreads();

    // ---- Phase 3a: chunk composition walks (0..14) + chunk 15 real walk ----
    {
        const int c = tid >> 4;
        const int i = tid & 15;
        if (c < 15 && i < KK) {
            int cur = i;
            for (int s = c * 32 + 31; s >= c * 32; --s) cur = psi_lds[s * KK + cur];
            comp[c * KK + i] = cur;            // path[32c] given path[32(c+1)] = i
        } else if (c == 15 && i == 0) {
            int cur = sh_last;
            float* po = out + BB + (size_t)b * TT;
            for (int s = TT - 2; s >= 480; --s) {
                cur = psi_lds[s * KK + cur];
                po[s] = (float)cur;
            }
            bt[15] = cur;                      // = path[480]
        }
    }
    __syncthreads();

    // ---- Phase 3b: boundary chain ----
    if (tid == 0) {
        for (int c = 14; c >= 1; --c) bt[c] = comp[c * KK + bt[c + 1]];
    }
    __syncthreads();

    // ---- Phase 3c: parallel re-walks, store path ----
    if (tid < 15) {
        const int c = tid;
        int cur = bt[c + 1];                   // path[32(c+1)]
        float* po = out + BB + (size_t)b * TT;
        for (int s = c * 32 + 31; s >= c * 32; --s) {
            cur = psi_lds[s * KK + cur];
            po[s] = (float)cur;
        }
    }
}

extern "C" void kernel_launch(void* const* d_in, const int* in_sizes, int n_in,
                              void* d_out, int out_size, void* d_ws, size_t ws_size,
                              hipStream_t stream) {
    const float* embeds = (const float*)d_in[0];  // [B,T,H]
    const float* W_fc   = (const float*)d_in[1];  // [K,H]
    const float* b_fc   = (const float*)d_in[2];  // [K]
    const float* trans  = (const float*)d_in[3];  // [K,K]
    float* out = (float*)d_out;                   // [B] score ++ [B,T] path (as float)
    float* feats = (float*)d_ws;                  // [B,T,K] scratch

    fc_kernel<<<1024, 256, 0, stream>>>(embeds, W_fc, b_fc, feats);
    viterbi_kernel<<<BB, 256, 0, stream>>>(feats, trans, out);
}